// Round 19
// baseline (442.476 us; speedup 1.0000x reference)
//
#include <hip/hip_runtime.h>

// Dilated conv2d, round 19: two independent barrier domains per CU.
// r18 budget closes as MFMA (53%) + LDS (49%) fully SERIALIZED; all waves in
// one barrier domain align their read/MFMA bursts (r17: even barrier-free
// waves in one domain don't drift). m114: separate scheduling entities DO
// overlap. Never isolated: every round since r12 ran ONE block/CU.
// This round: 256thr/4waves per block, wave = 64co x 128pos x own-row (ni=8),
// 4 rows/step, 8-slot ring 78.3KB -> TRUE 2 blocks/CU, A from L2 (r16-proven),
// ONE barrier/phase (stage issued after barrier into just-freed slot, drained
// by next phase's barrier; liveness: r'+wave in (r,8) never == r mod 8).

#define CIN 32
#define HH 512
#define WW 512
#define COUT 64
#define OH 508
#define OW 496
#define KH 5
#define KW 9

#define XT_H 516
#define XT_W 544
#define XSEC_E 4352              // elts per h-section of one xT row: 544*8
#define XT_ROWE 17408            // elts per (b,hp) row: 4 sections
#define XT_ELTS ((size_t)8 * XT_H * XT_ROWE)
#define XT_BYTES (XT_ELTS * 2)                 // 143,720,448
#define WREP_BYTES (KH * KW * COUT * CIN * 2)  // 184,320

#define WT2 128                  // pos tile per block
#define SEC_CH 153               // 16B chunks per h-section (152 data + 1 pad)
#define SLOT_E3 (4 * SEC_CH * 8) // 4896 elts = 9792 B per row slot
#define NSL4 8                   // ring slots -> 78,336 B -> 2 blocks/CU
#define RING_E4 (NSL4 * SLOT_E3)
#define NCH4 (4 * SEC_CH)        // 612 chunks per slot
#define STEPS4 8                 // 4 rows/step x 8 = 32 parity-rows/chunk

typedef short short8 __attribute__((ext_vector_type(8)));
typedef float floatx4 __attribute__((ext_vector_type(4)));
typedef unsigned short u16;
typedef unsigned int u32;

__device__ __forceinline__ u16 f2bf(float f) {  // RNE f32->bf16
    u32 u = __float_as_uint(f);
    return (u16)((u + 0x7fffu + ((u >> 16) & 1u)) >> 16);
}

__device__ __forceinline__ void gl2lds(const u16* g, u16* l) {
    __builtin_amdgcn_global_load_lds(
        (const __attribute__((address_space(1))) unsigned int*)g,
        (__attribute__((address_space(3))) unsigned int*)l, 16, 0, 0);
}

// [tap][co][cin] layout (r9/r16-proven global-A addressing)
__global__ void repack_w_k(const float* __restrict__ w, u16* __restrict__ wr) {
    int idx = blockIdx.x * 256 + threadIdx.x;
    if (idx >= KH * KW * COUT * CIN) return;
    int tap = idx / (COUT * CIN);
    int rem = idx - tap * (COUT * CIN);
    int co = rem / CIN;
    int ci = rem - co * CIN;
    int r  = tap / KW;
    int kw = tap - r * KW;
    wr[idx] = f2bf(w[((co * CIN + ci) * KH + r) * KW + kw]);
}

// K1: x -> xT [b][hp][h:4][wq:544][8cin] bf16, zero-padded borders.
__global__ __launch_bounds__(128)
void transpose_x(const float* __restrict__ x, u16* __restrict__ xT) {
    int pr = blockIdx.x * 128 + threadIdx.x;
    if (pr >= XT_W / 2) return;
    int wq = 2 * pr;
    int hp = blockIdx.y;
    int b  = blockIdx.z;
    int ih = hp - 2, iw0 = wq - 4;
    bool okh = (unsigned)ih < HH;
    bool ok0 = okh && ((unsigned)iw0 < WW);
    bool ok1 = okh && ((unsigned)(iw0 + 1) < WW);
    const float* xp = x + (size_t)b * CIN * (HH * WW) + (size_t)ih * WW + iw0;
    u16 v0[32], v1[32];
    if (ok0 && ok1) {
        #pragma unroll
        for (int c = 0; c < 32; ++c) {
            float2 f = *(const float2*)(xp + (size_t)c * (HH * WW));
            v0[c] = f2bf(f.x);
            v1[c] = f2bf(f.y);
        }
    } else {
        #pragma unroll
        for (int c = 0; c < 32; ++c) {
            v0[c] = ok0 ? f2bf(xp[(size_t)c * (HH * WW)]) : (u16)0;
            v1[c] = ok1 ? f2bf(xp[(size_t)c * (HH * WW) + 1]) : (u16)0;
        }
    }
    u16* dst = xT + ((size_t)b * XT_H + hp) * XT_ROWE + wq * 8;
    #pragma unroll
    for (int k = 0; k < 4; ++k)
        *(uint4*)(dst + (size_t)k * XSEC_E) = *(const uint4*)&v0[8 * k];
    #pragma unroll
    for (int k = 0; k < 4; ++k)
        *(uint4*)(dst + (size_t)k * XSEC_E + 8) = *(const uint4*)&v1[8 * k];
}

// K2: 256 thr / 4 waves, 2 blocks/CU, wave = 64co x 128pos x own row.
__global__ __launch_bounds__(256, 2)
void conv_lds(const u16* __restrict__ xT, const u16* __restrict__ wrep,
              float* __restrict__ out) {
    __shared__ u16 s[RING_E4];                 // 78,336 B

    const int wt     = blockIdx.x & 3;
    const int parity = blockIdx.x >> 2;
    const int chunk  = blockIdx.y;             // 0..7, 32 parity-rows each
    const int b      = blockIdx.z;
    const int w0     = wt * WT2;
    const int jbase  = 32 * chunk;

    const int tid  = threadIdx.x;
    const int lane = tid & 63;
    const int wave = tid >> 6;                 // 0..3 = own row
    const int li   = lane & 15;
    const int h    = lane >> 4;

    const u16* xbT = xT + (size_t)b * XT_H * XT_ROWE;

    // stage chunk cx (0..611) of local parity-row l_ into ring slot l_%8
    #define STAGE_CHUNK(l_, cx_) do {                                         \
        int hp_ = parity + 2 * (jbase + (l_)); if (hp_ > 515) hp_ = 515;      \
        int hs_ = (cx_) / SEC_CH;                                             \
        int wj_ = (cx_) - hs_ * SEC_CH;                                       \
        if (wj_ >= 152) wj_ = 0;                                              \
        gl2lds(xbT + (size_t)hp_ * XT_ROWE + hs_ * XSEC_E + (w0 + wj_) * 8,   \
               &s[((l_) % NSL4) * SLOT_E3] + (cx_) * 8);                      \
    } while (0)

    // ---- prologue: rows 0..7 (4896 chunks, 256 thr -> 20 iters) ----
    #pragma unroll 1
    for (int k = 0; k < 20; ++k) {
        int c = tid + 256 * k;
        if (c < 8 * NCH4) STAGE_CHUNK(c / NCH4, c % NCH4);
    }
    __syncthreads();

    // A: global [tap][co][cin]: aw + (r*9+kw)*2048 + mi*16*32 elts
    const u16* aw = wrep + li * CIN + 8 * h;
    // B: ring [h:4][153ch][8]: slot + h*1224 + (li + 16ni + 3kw)*8
    const int bbase = h * (SEC_CH * 8) + li * 8;

    floatx4 acc[4][8];

    #pragma unroll 1
    for (int st = 0; st < STEPS4; ++st) {
        #pragma unroll
        for (int mi = 0; mi < 4; ++mi)
            #pragma unroll
            for (int ni = 0; ni < 8; ++ni)
                acc[mi][ni] = (floatx4){0.f, 0.f, 0.f, 0.f};

        #pragma unroll 1
        for (int r = 0; r < KH; ++r) {
            // ---- compute phase r: 9 kw x (4 A-L2 + 8 B-ds + 32 MFMA) ----
            const int jj = 4 * st + wave + r;
            const u16* bb = &s[(jj % NSL4) * SLOT_E3] + bbase;
            const u16* ab = aw + (size_t)(r * KW) * (COUT * CIN);
            #pragma unroll
            for (int kw = 0; kw < KW; ++kw) {
                short8 af[4], bf_[8];
                #pragma unroll
                for (int mi = 0; mi < 4; ++mi)
                    af[mi] = *(const short8*)(ab + (kw * COUT + mi * 16) * CIN);
                #pragma unroll
                for (int ni = 0; ni < 8; ++ni)
                    bf_[ni] = *(const short8*)(bb + (16 * ni + 3 * kw) * 8);
                __builtin_amdgcn_s_setprio(1);
                #pragma unroll
                for (int mi = 0; mi < 4; ++mi)
                    #pragma unroll
                    for (int ni = 0; ni < 8; ++ni)
                        acc[mi][ni] = __builtin_amdgcn_mfma_f32_16x16x32_bf16(
                            af[mi], bf_[ni], acc[mi][ni], 0, 0, 0);
                __builtin_amdgcn_s_setprio(0);
            }

            // ---- ONE barrier/phase: confirms slot (4st+r)%8 is dead AND
            // drains the stage issued at phase r-1 (T14 issue-early). ----
            __syncthreads();

            // stage row 4st+8+r into the just-freed slot; drained by the
            // NEXT phase's barrier; first read is step st+1.
            if (r < 4 && st < STEPS4 - 1) {
                #pragma unroll 1
                for (int k = 0; k < 3; ++k) {
                    int c = tid + 256 * k;
                    if (c < NCH4) STAGE_CHUNK(4 * st + 8 + r, c);
                }
            }
        }

        // ---- store this step's row (wave owns full 128-pos tile) ----
        const int oh = parity + 2 * (jbase + 4 * st + wave);
        if (oh < OH) {
            #pragma unroll
            for (int ni = 0; ni < 8; ++ni) {
                const int posb = w0 + 16 * ni;
                if (posb < OW) {
                    const int pos = posb + li;
                    #pragma unroll
                    for (int mi = 0; mi < 4; ++mi) {
                        float* op = out + (((size_t)(b * COUT + 16 * mi + 4 * h) * OH + oh) * OW) + pos;
                        #pragma unroll
                        for (int reg = 0; reg < 4; ++reg)
                            op[(size_t)reg * OH * OW] = acc[mi][ni][reg];
                    }
                }
            }
        }
    }
    #undef STAGE_CHUNK
}

// ---------------- Fallback: round-9 parity-ring kernel ----------------
#define WTILE 128
#define SW 152
#define OCT_STRIDE 1224
#define SLOT_STRIDE 4896
#define NSLOT 8
#define NIT 304
#define STEPS 16

__global__ __launch_bounds__(256, 2)
void conv_ring(const float* __restrict__ x, const u16* __restrict__ wrep,
               float* __restrict__ out) {
    __shared__ u16 s[NSLOT * SLOT_STRIDE];

    const int bx     = blockIdx.x;
    const int wt     = bx & 3;
    const int parity = bx >> 2;
    const int chunk  = blockIdx.y;
    const int b      = blockIdx.z;
    const int w0     = wt * WTILE;
    const int oh0    = parity + 64 * chunk;
    const int ihbase = oh0 - 2;
    const int iwbase = w0 - 4;

    const int tid  = threadIdx.x;
    const int lane = tid & 63;
    const int wave = tid >> 6;
    const int wp   = wave & 1;
    const int wo   = wave >> 1;
    const int li   = lane & 15;
    const int h    = lane >> 4;

    const size_t cstr = (size_t)HH * WW;
    const float* xb = x + (size_t)b * CIN * cstr;

    for (int it = tid; it < 6 * NIT; it += 256) {
        int j   = it / NIT;
        int rem = it - j * NIT;
        int w4  = rem >> 3;
        int q   = rem & 7;
        int ih  = ihbase + 2 * j;
        int iw0 = iwbase + 4 * w4;
        float4 m0 = {0,0,0,0}, m1 = {0,0,0,0}, m2 = {0,0,0,0}, m3 = {0,0,0,0};
        if ((unsigned)ih < HH && (unsigned)iw0 < WW) {
            const float* pp = xb + (size_t)(4 * q) * cstr + (size_t)ih * WW + iw0;
            m0 = *(const float4*)(pp);
            m1 = *(const float4*)(pp + cstr);
            m2 = *(const float4*)(pp + 2 * cstr);
            m3 = *(const float4*)(pp + 3 * cstr);
        }
        u16* dst = s + (j & 7) * SLOT_STRIDE + (q >> 1) * OCT_STRIDE + (q & 1) * 4;
        const float* f0 = (const float*)&m0; const float* f1 = (const float*)&m1;
        const float* f2 = (const float*)&m2; const float* f3 = (const float*)&m3;
        #pragma unroll
        for (int jj = 0; jj < 4; ++jj) {
            u32 lo = (u32)f2bf(f0[jj]) | ((u32)f2bf(f1[jj]) << 16);
            u32 hi = (u32)f2bf(f2[jj]) | ((u32)f2bf(f3[jj]) << 16);
            *(uint2*)(dst + (4 * w4 + jj) * 8) = make_uint2(lo, hi);
        }
    }
    __syncthreads();

    const u16* abase0 = wrep + li * CIN + 8 * h;
    const int  bfixed = h * OCT_STRIDE + (64 * wp + li) * 8;

    floatx4 acc[4][4];

    #pragma unroll 1
    for (int st = 0; st < STEPS; ++st) {
        #pragma unroll
        for (int mi = 0; mi < 4; ++mi)
            #pragma unroll
            for (int ni = 0; ni < 4; ++ni)
                acc[mi][ni] = (floatx4){0.f, 0.f, 0.f, 0.f};

        const bool doPref = (st < STEPS - 1);
        float4 pv[3][4];
        #pragma unroll
        for (int k = 0; k < 3; ++k) {
            #pragma unroll
            for (int c = 0; c < 4; ++c) pv[k][c] = (float4){0,0,0,0};
            int it = tid + 256 * k;
            if (doPref && it < 2 * NIT) {
                int second = (it >= NIT);
                int rem = it - (second ? NIT : 0);
                int j   = 2 * st + 6 + second;
                int w4  = rem >> 3;
                int q   = rem & 7;
                int ih  = ihbase + 2 * j;
                int iw0 = iwbase + 4 * w4;
                if ((unsigned)ih < HH && (unsigned)iw0 < WW) {
                    const float* pp = xb + (size_t)(4 * q) * cstr + (size_t)ih * WW + iw0;
                    pv[k][0] = *(const float4*)(pp);
                    pv[k][1] = *(const float4*)(pp + cstr);
                    pv[k][2] = *(const float4*)(pp + 2 * cstr);
                    pv[k][3] = *(const float4*)(pp + 3 * cstr);
                }
            }
        }

        const int js = 2 * st;
        #pragma unroll 1
        for (int r = 0; r < KH; ++r) {
            const u16* bb = s + ((js + wo + r) & 7) * SLOT_STRIDE + bfixed;
            const u16* ab = abase0 + (size_t)(r * KW) * (COUT * CIN);
            #pragma unroll
            for (int kw = 0; kw < KW; ++kw) {
                short8 af[4], bf_[4];
                #pragma unroll
                for (int mi = 0; mi < 4; ++mi)
                    af[mi] = *(const short8*)(ab + (kw * COUT + mi * 16) * CIN);
                #pragma unroll
                for (int ni = 0; ni < 4; ++ni)
                    bf_[ni] = *(const short8*)(bb + (16 * ni + 3 * kw) * 8);
                __builtin_amdgcn_s_setprio(1);
                #pragma unroll
                for (int mi = 0; mi < 4; ++mi)
                    #pragma unroll
                    for (int ni = 0; ni < 4; ++ni)
                        acc[mi][ni] = __builtin_amdgcn_mfma_f32_16x16x32_bf16(
                            af[mi], bf_[ni], acc[mi][ni], 0, 0, 0);
                __builtin_amdgcn_s_setprio(0);
            }
        }

        if (doPref) {
            #pragma unroll
            for (int k = 0; k < 3; ++k) {
                int it = tid + 256 * k;
                if (it < 2 * NIT) {
                    int second = (it >= NIT);
                    int rem = it - (second ? NIT : 0);
                    int j   = 2 * st + 6 + second;
                    int w4  = rem >> 3;
                    int q   = rem & 7;
                    u16* dst = s + (j & 7) * SLOT_STRIDE + (q >> 1) * OCT_STRIDE + (q & 1) * 4;
                    const float* f0 = (const float*)&pv[k][0];
                    const float* f1 = (const float*)&pv[k][1];
                    const float* f2 = (const float*)&pv[k][2];
                    const float* f3 = (const float*)&pv[k][3];
                    #pragma unroll
                    for (int jj = 0; jj < 4; ++jj) {
                        u32 lo = (u32)f2bf(f0[jj]) | ((u32)f2bf(f1[jj]) << 16);
                        u32 hi = (u32)f2bf(f2[jj]) | ((u32)f2bf(f3[jj]) << 16);
                        *(uint2*)(dst + (4 * w4 + jj) * 8) = make_uint2(lo, hi);
                    }
                }
            }
        }
        __syncthreads();

        const int oh = oh0 + 4 * st + 2 * wo;
        if (oh < OH) {
            #pragma unroll
            for (int ni = 0; ni < 4; ++ni) {
                const int posb = w0 + 64 * wp + 16 * ni;
                if (posb < OW) {
                    const int pos = posb + li;
                    #pragma unroll
                    for (int mi = 0; mi < 4; ++mi) {
                        float* op = out + (((size_t)(b * COUT + 16 * mi + 4 * h) * OH + oh) * OW) + pos;
                        #pragma unroll
                        for (int reg = 0; reg < 4; ++reg)
                            op[(size_t)reg * OH * OW] = acc[mi][ni][reg];
                    }
                }
            }
        }
    }
}

extern "C" void kernel_launch(void* const* d_in, const int* in_sizes, int n_in,
                              void* d_out, int out_size, void* d_ws, size_t ws_size,
                              hipStream_t stream) {
    const float* x = (const float*)d_in[0];
    const float* w = (const float*)d_in[1];
    float* out = (float*)d_out;

    if (ws_size >= XT_BYTES + WREP_BYTES) {
        u16* xT   = (u16*)d_ws;
        u16* wrep = (u16*)((char*)d_ws + XT_BYTES);
        repack_w_k<<<(KH * KW * COUT * CIN + 255) / 256, 256, 0, stream>>>(w, wrep);
        dim3 tg((XT_W / 2 + 127) / 128, XT_H, 8);
        transpose_x<<<tg, 128, 0, stream>>>(x, xT);
        dim3 cg(8 /* wt(4) x parity(2) */, 8 /* chunks */, 8 /* batch */);
        conv_lds<<<cg, dim3(256), 0, stream>>>(xT, wrep, out);
    } else {
        u16* wrep = (u16*)d_ws;
        repack_w_k<<<(KH * KW * COUT * CIN + 255) / 256, 256, 0, stream>>>(w, wrep);
        dim3 grid(8, 8, 8);
        conv_ring<<<grid, dim3(256), 0, stream>>>(x, wrep, out);
    }
}

// Round 20
// 418.006 us; speedup vs baseline: 1.0585x; 1.0585x over previous
//
#include <hip/hip_runtime.h>

// Dilated conv2d, round 20: REVERT to round-18 (session best, 419.6us).
// r19 falsified the last open theory (independent barrier domains: 372us,
// MfmaUtil 45.7 < r18's 350us/49.3). Ledger complete: LDS-bytes x, TLP x,
// conflicts x, barrier-count x, barrier-domains x, A-source x. r18 is the
// 2-barrier-class ceiling (~50% MfmaUtil, conv ~1061 TF = 42% dense peak).
// Structure: 512thr/8waves, 1 block/CU, wave = 64co x 128pos x own-row,
// 8 rows/step, 12-slot ring + single wbuf (oct-major conflict-free layouts),
// all operands from LDS via global_load_lds DMA staging.

#define CIN 32
#define HH 512
#define WW 512
#define COUT 64
#define OH 508
#define OW 496
#define KH 5
#define KW 9

#define XT_H 516
#define XT_W 544
#define XSEC_E 4352              // elts per h-section of one xT row: 544*8
#define XT_ROWE 17408            // elts per (b,hp) row: 4 sections
#define XT_ELTS ((size_t)8 * XT_H * XT_ROWE)
#define XT_BYTES (XT_ELTS * 2)                 // 143,720,448
#define WREP_BYTES (KH * KW * COUT * CIN * 2)  // 184,320

#define WT2 128                  // pos tile per block
#define SEC_CH 161               // 16B chunks per h-section (160 data + 1 pad)
#define SLOT_E2 (4 * SEC_CH * 8) // 5152 elts = 10,304B per row slot
#define NSL 12                   // ring slots
#define RING_E2 (NSL * SLOT_E2)  // 61,824 elts = 123,648 B
#define NCH 644                  // chunks per slot: 4*161
#define WSEC_E 4608              // wbuf h-section elts: 576*8
#define WBUF_E2 (4 * WSEC_E)     // 18,432 elts = 36,864 B
#define STEPS2 8                 // 8 rows/step x 8 steps = 64 parity-rows

typedef short short8 __attribute__((ext_vector_type(8)));
typedef float floatx4 __attribute__((ext_vector_type(4)));
typedef unsigned short u16;
typedef unsigned int u32;

__device__ __forceinline__ u16 f2bf(float f) {  // RNE f32->bf16
    u32 u = __float_as_uint(f);
    return (u16)((u + 0x7fffu + ((u >> 16) & 1u)) >> 16);
}

__device__ __forceinline__ void gl2lds(const u16* g, u16* l) {
    __builtin_amdgcn_global_load_lds(
        (const __attribute__((address_space(1))) unsigned int*)g,
        (__attribute__((address_space(3))) unsigned int*)l, 16, 0, 0);
}

// oct-major weights: wr[((r*4+h)*576 + kw*64 + co)*8 + j] = w[co][8h+j][r][kw]
__global__ void repack_w_oct(const float* __restrict__ w, u16* __restrict__ wr) {
    int idx = blockIdx.x * 256 + threadIdx.x;
    if (idx >= KH * KW * COUT * CIN) return;
    int j  = idx & 7;
    int c2 = idx >> 3;
    int co = c2 & 63;
    int t  = c2 >> 6;
    int kw = t % KW;
    int t2 = t / KW;
    int h  = t2 & 3;
    int r  = t2 >> 2;
    wr[idx] = f2bf(w[((co * CIN + 8 * h + j) * KH + r) * KW + kw]);
}

// old layout for fallback
__global__ void repack_w_old(const float* __restrict__ w, u16* __restrict__ wr) {
    int idx = blockIdx.x * 256 + threadIdx.x;
    if (idx >= KH * KW * COUT * CIN) return;
    int tap = idx / (COUT * CIN);
    int rem = idx - tap * (COUT * CIN);
    int co = rem / CIN;
    int ci = rem - co * CIN;
    int r  = tap / KW;
    int kw = tap - r * KW;
    wr[idx] = f2bf(w[((co * CIN + ci) * KH + r) * KW + kw]);
}

// K1: x -> xT [b][hp][h:4][wq:544][8cin] bf16, zero-padded borders.
__global__ __launch_bounds__(128)
void transpose_x(const float* __restrict__ x, u16* __restrict__ xT) {
    int pr = blockIdx.x * 128 + threadIdx.x;
    if (pr >= XT_W / 2) return;
    int wq = 2 * pr;
    int hp = blockIdx.y;
    int b  = blockIdx.z;
    int ih = hp - 2, iw0 = wq - 4;
    bool okh = (unsigned)ih < HH;
    bool ok0 = okh && ((unsigned)iw0 < WW);
    bool ok1 = okh && ((unsigned)(iw0 + 1) < WW);
    const float* xp = x + (size_t)b * CIN * (HH * WW) + (size_t)ih * WW + iw0;
    u16 v0[32], v1[32];
    if (ok0 && ok1) {
        #pragma unroll
        for (int c = 0; c < 32; ++c) {
            float2 f = *(const float2*)(xp + (size_t)c * (HH * WW));
            v0[c] = f2bf(f.x);
            v1[c] = f2bf(f.y);
        }
    } else {
        #pragma unroll
        for (int c = 0; c < 32; ++c) {
            v0[c] = ok0 ? f2bf(xp[(size_t)c * (HH * WW)]) : (u16)0;
            v1[c] = ok1 ? f2bf(xp[(size_t)c * (HH * WW) + 1]) : (u16)0;
        }
    }
    u16* dst = xT + ((size_t)b * XT_H + hp) * XT_ROWE + wq * 8;
    #pragma unroll
    for (int k = 0; k < 4; ++k)
        *(uint4*)(dst + (size_t)k * XSEC_E) = *(const uint4*)&v0[8 * k];
    #pragma unroll
    for (int k = 0; k < 4; ++k)
        *(uint4*)(dst + (size_t)k * XSEC_E + 8) = *(const uint4*)&v1[8 * k];
}

// K2: 512 thr / 8 waves, 1 block/CU, wave = 64co x 128pos x own row.
__global__ __launch_bounds__(512, 1)
void conv_lds(const u16* __restrict__ xT, const u16* __restrict__ wrep,
              float* __restrict__ out) {
    __shared__ u16 s[RING_E2 + WBUF_E2];       // 160,512 B

    const int wt     = blockIdx.x & 3;
    const int parity = blockIdx.x >> 2;
    const int chunk  = blockIdx.y;             // 0..3, 64 parity-rows each
    const int b      = blockIdx.z;
    const int w0     = wt * WT2;
    const int jbase  = 64 * chunk;

    const int tid  = threadIdx.x;
    const int lane = tid & 63;
    const int wave = tid >> 6;                 // 0..7 = own row (wro)
    const int li   = lane & 15;
    const int h    = lane >> 4;

    u16* wb = &s[RING_E2];
    const u16* xbT = xT + (size_t)b * XT_H * XT_ROWE;

    // stage chunk cx (0..643) of local parity-row l_ into ring slot l_%12
    #define STAGE_CHUNK(l_, cx_) do {                                         \
        int hp_ = parity + 2 * (jbase + (l_)); if (hp_ > 515) hp_ = 515;      \
        int hs_ = (cx_) / SEC_CH;                                             \
        int wj_ = (cx_) - hs_ * SEC_CH;                                       \
        if (wj_ >= 160) wj_ = 0;                                              \
        gl2lds(xbT + (size_t)hp_ * XT_ROWE + hs_ * XSEC_E + (w0 + wj_) * 8,   \
               &s[((l_) % NSL) * SLOT_E2] + (cx_) * 8);                       \
    } while (0)

    // stage weights for r-row r_ into wbuf (2304 chunks, linear copy)
    #define STAGE_W(r_) do {                                                  \
        const u16* src_ = wrep + (size_t)(r_) * WBUF_E2;                      \
        _Pragma("unroll")                                                     \
        for (int k_ = 0; k_ < 5; ++k_) {                                      \
            int c_ = tid + 512 * k_;                                          \
            if (c_ < 2304) gl2lds(src_ + c_ * 8, wb + c_ * 8);                \
        }                                                                     \
    } while (0)

    // ---- prologue: rows 0..11 (7728 chunks) + weights r=0 ----
    #pragma unroll 1
    for (int k = 0; k < 16; ++k) {
        int c = tid + 512 * k;
        if (c < 12 * NCH) STAGE_CHUNK(c / NCH, c % NCH);
    }
    STAGE_W(0);
    __syncthreads();

    // A: wb + h*4608 + (kw*64 + mi*16 + li)*8  (quad -> 4 consecutive 16B grps)
    const int abase = h * WSEC_E + li * 8;
    // B: slot + h*1288 + (li + 16ni + 3kw)*8
    const int bbase = h * (SEC_CH * 8) + li * 8;

    floatx4 acc[4][8];

    #pragma unroll 1
    for (int st = 0; st < STEPS2; ++st) {
        #pragma unroll
        for (int mi = 0; mi < 4; ++mi)
            #pragma unroll
            for (int ni = 0; ni < 8; ++ni)
                acc[mi][ni] = (floatx4){0.f, 0.f, 0.f, 0.f};

        #pragma unroll 1
        for (int r = 0; r < KH; ++r) {
            // ---- compute phase r: 9 kw x (4 A + 8 B ds_read_b128 + 32 MFMA)
            const int jj = 8 * st + wave + r;
            const u16* bb = &s[(jj % NSL) * SLOT_E2] + bbase;
            const u16* ab = wb + abase;
            #pragma unroll
            for (int kw = 0; kw < KW; ++kw) {
                short8 af[4], bf_[8];
                #pragma unroll
                for (int mi = 0; mi < 4; ++mi)
                    af[mi] = *(const short8*)(ab + (kw * 64 + mi * 16) * 8);
                #pragma unroll
                for (int ni = 0; ni < 8; ++ni)
                    bf_[ni] = *(const short8*)(bb + (16 * ni + 3 * kw) * 8);
                __builtin_amdgcn_s_setprio(1);
                #pragma unroll
                for (int mi = 0; mi < 4; ++mi)
                    #pragma unroll
                    for (int ni = 0; ni < 8; ++ni)
                        acc[mi][ni] = __builtin_amdgcn_mfma_f32_16x16x32_bf16(
                            af[mi], bf_[ni], acc[mi][ni], 0, 0, 0);
                __builtin_amdgcn_s_setprio(0);
            }

            __syncthreads();                   // waves done with wbuf(r)/freed rows
            if (st < STEPS2 - 1) {
                if (r < 4) {
                    // row 8st+12+r -> slot of row 8st+r (freed after phase r)
                    #pragma unroll 1
                    for (int k = 0; k < 2; ++k) {
                        int c = tid + 512 * k;
                        if (c < NCH) STAGE_CHUNK(8 * st + 12 + r, c);
                    }
                } else {
                    // rows 8st+16..19 -> slots of rows 8st+4..7 (freed phase 4)
                    #pragma unroll 1
                    for (int k = 0; k < 6; ++k) {
                        int c = tid + 512 * k;
                        if (c < 4 * NCH)
                            STAGE_CHUNK(8 * st + 16 + c / NCH, c % NCH);
                    }
                }
            }
            if (r < 4) STAGE_W(r + 1);
            else if (st < STEPS2 - 1) STAGE_W(0);
            __syncthreads();                   // vmcnt(0) drain + barrier
        }

        // ---- store this step's row (wave owns full 128-pos tile) ----
        const int oh = parity + 2 * (jbase + 8 * st + wave);
        if (oh < OH) {
            #pragma unroll
            for (int ni = 0; ni < 8; ++ni) {
                const int posb = w0 + 16 * ni;
                if (posb < OW) {
                    const int pos = posb + li;
                    #pragma unroll
                    for (int mi = 0; mi < 4; ++mi) {
                        float* op = out + (((size_t)(b * COUT + 16 * mi + 4 * h) * OH + oh) * OW) + pos;
                        #pragma unroll
                        for (int reg = 0; reg < 4; ++reg)
                            op[(size_t)reg * OH * OW] = acc[mi][ni][reg];
                    }
                }
            }
        }
    }
    #undef STAGE_CHUNK
    #undef STAGE_W
}

// ---------------- Fallback: round-9 parity-ring kernel ----------------
#define WTILE 128
#define SW 152
#define OCT_STRIDE 1224
#define SLOT_STRIDE 4896
#define NSLOT 8
#define NIT 304
#define STEPS 16

__global__ __launch_bounds__(256, 2)
void conv_ring(const float* __restrict__ x, const u16* __restrict__ wrep,
               float* __restrict__ out) {
    __shared__ u16 s[NSLOT * SLOT_STRIDE];

    const int bx     = blockIdx.x;
    const int wt     = bx & 3;
    const int parity = bx >> 2;
    const int chunk  = blockIdx.y;
    const int b      = blockIdx.z;
    const int w0     = wt * WTILE;
    const int oh0    = parity + 64 * chunk;
    const int ihbase = oh0 - 2;
    const int iwbase = w0 - 4;

    const int tid  = threadIdx.x;
    const int lane = tid & 63;
    const int wave = tid >> 6;
    const int wp   = wave & 1;
    const int wo   = wave >> 1;
    const int li   = lane & 15;
    const int h    = lane >> 4;

    const size_t cstr = (size_t)HH * WW;
    const float* xb = x + (size_t)b * CIN * cstr;

    for (int it = tid; it < 6 * NIT; it += 256) {
        int j   = it / NIT;
        int rem = it - j * NIT;
        int w4  = rem >> 3;
        int q   = rem & 7;
        int ih  = ihbase + 2 * j;
        int iw0 = iwbase + 4 * w4;
        float4 m0 = {0,0,0,0}, m1 = {0,0,0,0}, m2 = {0,0,0,0}, m3 = {0,0,0,0};
        if ((unsigned)ih < HH && (unsigned)iw0 < WW) {
            const float* pp = xb + (size_t)(4 * q) * cstr + (size_t)ih * WW + iw0;
            m0 = *(const float4*)(pp);
            m1 = *(const float4*)(pp + cstr);
            m2 = *(const float4*)(pp + 2 * cstr);
            m3 = *(const float4*)(pp + 3 * cstr);
        }
        u16* dst = s + (j & 7) * SLOT_STRIDE + (q >> 1) * OCT_STRIDE + (q & 1) * 4;
        const float* f0 = (const float*)&m0; const float* f1 = (const float*)&m1;
        const float* f2 = (const float*)&m2; const float* f3 = (const float*)&m3;
        #pragma unroll
        for (int jj = 0; jj < 4; ++jj) {
            u32 lo = (u32)f2bf(f0[jj]) | ((u32)f2bf(f1[jj]) << 16);
            u32 hi = (u32)f2bf(f2[jj]) | ((u32)f2bf(f3[jj]) << 16);
            *(uint2*)(dst + (4 * w4 + jj) * 8) = make_uint2(lo, hi);
        }
    }
    __syncthreads();

    const u16* abase0 = wrep + li * CIN + 8 * h;
    const int  bfixed = h * OCT_STRIDE + (64 * wp + li) * 8;

    floatx4 acc[4][4];

    #pragma unroll 1
    for (int st = 0; st < STEPS; ++st) {
        #pragma unroll
        for (int mi = 0; mi < 4; ++mi)
            #pragma unroll
            for (int ni = 0; ni < 4; ++ni)
                acc[mi][ni] = (floatx4){0.f, 0.f, 0.f, 0.f};

        const bool doPref = (st < STEPS - 1);
        float4 pv[3][4];
        #pragma unroll
        for (int k = 0; k < 3; ++k) {
            #pragma unroll
            for (int c = 0; c < 4; ++c) pv[k][c] = (float4){0,0,0,0};
            int it = tid + 256 * k;
            if (doPref && it < 2 * NIT) {
                int second = (it >= NIT);
                int rem = it - (second ? NIT : 0);
                int j   = 2 * st + 6 + second;
                int w4  = rem >> 3;
                int q   = rem & 7;
                int ih  = ihbase + 2 * j;
                int iw0 = iwbase + 4 * w4;
                if ((unsigned)ih < HH && (unsigned)iw0 < WW) {
                    const float* pp = xb + (size_t)(4 * q) * cstr + (size_t)ih * WW + iw0;
                    pv[k][0] = *(const float4*)(pp);
                    pv[k][1] = *(const float4*)(pp + cstr);
                    pv[k][2] = *(const float4*)(pp + 2 * cstr);
                    pv[k][3] = *(const float4*)(pp + 3 * cstr);
                }
            }
        }

        const int js = 2 * st;
        #pragma unroll 1
        for (int r = 0; r < KH; ++r) {
            const u16* bb = s + ((js + wo + r) & 7) * SLOT_STRIDE + bfixed;
            const u16* ab = abase0 + (size_t)(r * KW) * (COUT * CIN);
            #pragma unroll
            for (int kw = 0; kw < KW; ++kw) {
                short8 af[4], bf_[4];
                #pragma unroll
                for (int mi = 0; mi < 4; ++mi)
                    af[mi] = *(const short8*)(ab + (kw * COUT + mi * 16) * CIN);
                #pragma unroll
                for (int ni = 0; ni < 4; ++ni)
                    bf_[ni] = *(const short8*)(bb + (16 * ni + 3 * kw) * 8);
                __builtin_amdgcn_s_setprio(1);
                #pragma unroll
                for (int mi = 0; mi < 4; ++mi)
                    #pragma unroll
                    for (int ni = 0; ni < 4; ++ni)
                        acc[mi][ni] = __builtin_amdgcn_mfma_f32_16x16x32_bf16(
                            af[mi], bf_[ni], acc[mi][ni], 0, 0, 0);
                __builtin_amdgcn_s_setprio(0);
            }
        }

        if (doPref) {
            #pragma unroll
            for (int k = 0; k < 3; ++k) {
                int it = tid + 256 * k;
                if (it < 2 * NIT) {
                    int second = (it >= NIT);
                    int rem = it - (second ? NIT : 0);
                    int j   = 2 * st + 6 + second;
                    int w4  = rem >> 3;
                    int q   = rem & 7;
                    u16* dst = s + (j & 7) * SLOT_STRIDE + (q >> 1) * OCT_STRIDE + (q & 1) * 4;
                    const float* f0 = (const float*)&pv[k][0];
                    const float* f1 = (const float*)&pv[k][1];
                    const float* f2 = (const float*)&pv[k][2];
                    const float* f3 = (const float*)&pv[k][3];
                    #pragma unroll
                    for (int jj = 0; jj < 4; ++jj) {
                        u32 lo = (u32)f2bf(f0[jj]) | ((u32)f2bf(f1[jj]) << 16);
                        u32 hi = (u32)f2bf(f2[jj]) | ((u32)f2bf(f3[jj]) << 16);
                        *(uint2*)(dst + (4 * w4 + jj) * 8) = make_uint2(lo, hi);
                    }
                }
            }
        }
        __syncthreads();

        const int oh = oh0 + 4 * st + 2 * wo;
        if (oh < OH) {
            #pragma unroll
            for (int ni = 0; ni < 4; ++ni) {
                const int posb = w0 + 64 * wp + 16 * ni;
                if (posb < OW) {
                    const int pos = posb + li;
                    #pragma unroll
                    for (int mi = 0; mi < 4; ++mi) {
                        float* op = out + (((size_t)(b * COUT + 16 * mi + 4 * h) * OH + oh) * OW) + pos;
                        #pragma unroll
                        for (int reg = 0; reg < 4; ++reg)
                            op[(size_t)reg * OH * OW] = acc[mi][ni][reg];
                    }
                }
            }
        }
    }
}

extern "C" void kernel_launch(void* const* d_in, const int* in_sizes, int n_in,
                              void* d_out, int out_size, void* d_ws, size_t ws_size,
                              hipStream_t stream) {
    const float* x = (const float*)d_in[0];
    const float* w = (const float*)d_in[1];
    float* out = (float*)d_out;

    if (ws_size >= XT_BYTES + WREP_BYTES) {
        u16* xT   = (u16*)d_ws;
        u16* wrep = (u16*)((char*)d_ws + XT_BYTES);
        repack_w_oct<<<(KH * KW * COUT * CIN + 255) / 256, 256, 0, stream>>>(w, wrep);
        dim3 tg((XT_W / 2 + 127) / 128, XT_H, 8);
        transpose_x<<<tg, 128, 0, stream>>>(x, xT);
        dim3 cg(8 /* wt(4) x parity(2) */, 4 /* chunks */, 8 /* batch */);
        conv_lds<<<cg, dim3(512), 0, stream>>>(xT, wrep, out);
    } else {
        u16* wrep = (u16*)d_ws;
        repack_w_old<<<(KH * KW * COUT * CIN + 255) / 256, 256, 0, stream>>>(w, wrep);
        dim3 grid(8, 8, 8);
        conv_ring<<<grid, dim3(256), 0, stream>>>(x, wrep, out);
    }
}